// Round 3
// baseline (223.091 us; speedup 1.0000x reference)
//
#include <hip/hip_runtime.h>

// Hadamard on qubit TARGET=5 of N_QUBITS=24, batch=2, real float32 state.
// Per batch: L = 32, R = 2^18 floats. Pair stride = R floats = 1 MiB.
// y0 = (x0 + x1)/sqrt2 ; y1 = (x0 - x1)/sqrt2.
//
// R3: same as R1 (2 pairs/thread, 4 independent 16B loads, nontemporal)
// but using native clang vector type — HIP's float4 is a class and the
// nontemporal builtins reject it.

typedef float floatx4 __attribute__((ext_vector_type(4)));

__global__ __launch_bounds__(256) void hgate_kernel(const floatx4* __restrict__ x,
                                                    floatx4* __restrict__ y) {
    constexpr int R4_LOG2 = 16;                  // R/4 = 65536 float4 elements
    constexpr int R4 = 1 << R4_LOG2;
    constexpr int HALF_BL = 32;                  // bl in [0,64); split at 32 (= batch dim)
    const float s = 0.70710678118654752440f;

    int t = blockIdx.x * blockDim.x + threadIdx.x;   // t in [0, 2^21)
    int r4 = t & (R4 - 1);
    int bl = t >> R4_LOG2;                       // [0, 32)

    int idx0a = (bl << (R4_LOG2 + 1)) + r4;      // pair A, low half
    int idx1a = idx0a + R4;
    int idx0b = ((bl + HALF_BL) << (R4_LOG2 + 1)) + r4;  // pair B (other batch)
    int idx1b = idx0b + R4;

    // 4 independent loads issued before any use
    floatx4 a0 = __builtin_nontemporal_load(&x[idx0a]);
    floatx4 a1 = __builtin_nontemporal_load(&x[idx1a]);
    floatx4 b0 = __builtin_nontemporal_load(&x[idx0b]);
    floatx4 b1 = __builtin_nontemporal_load(&x[idx1b]);

    floatx4 ya0 = (a0 + a1) * s;
    floatx4 ya1 = (a0 - a1) * s;
    floatx4 yb0 = (b0 + b1) * s;
    floatx4 yb1 = (b0 - b1) * s;

    __builtin_nontemporal_store(ya0, &y[idx0a]);
    __builtin_nontemporal_store(ya1, &y[idx1a]);
    __builtin_nontemporal_store(yb0, &y[idx0b]);
    __builtin_nontemporal_store(yb1, &y[idx1b]);
}

extern "C" void kernel_launch(void* const* d_in, const int* in_sizes, int n_in,
                              void* d_out, int out_size, void* d_ws, size_t ws_size,
                              hipStream_t stream) {
    const floatx4* x = (const floatx4*)d_in[0];
    floatx4* y = (floatx4*)d_out;
    // 2^23 float4 pairs total / 2 pairs per thread = 2^21 threads
    const int total_threads = 1 << 21;
    const int block = 256;
    const int grid = total_threads / block;      // 8192
    hgate_kernel<<<grid, block, 0, stream>>>(x, y);
}